// Round 5
// baseline (18.177 us; speedup 1.0000x reference)
//
#include <hip/hip_runtime.h>
#include <math.h>

#define HEADS 8
#define BATCH 4
#define SEQ 2048
#define CDIM 32
#define WINDOW 10
#define WSZ 21                       // keys per query row
#define RPB 32                       // query rows per block
#define BAND (RPB + 2 * WINDOW)      // 52 band rows (K staged in LDS)

// DPP cross-lane add (pure VALU). xor1 = quad_perm 0xB1, xor2 = quad_perm
// 0x4E, cross-quad within 8-lane group = row_half_mirror 0x141.
#define DPP_ADD(x, ctrl) \
    ((x) + __int_as_float(__builtin_amdgcn_mov_dpp(__float_as_int(x), (ctrl), 0xF, 0xF, true)))

// Pipe-split design: K band via LDS (DS pipe), V band via global (L1/TA pipe),
// so the 2x256B-per-(row,key) stream is spread over two independent pipes.
__global__ __launch_bounds__(256) void lwin_attn_kernel(
    const float* __restrict__ Q, const float* __restrict__ K,
    const float* __restrict__ V, const float* __restrict__ G,
    const unsigned char* __restrict__ seqMask, float* __restrict__ out)
{
    __shared__ float k_lds[BAND][CDIM];   // 6656 B
    __shared__ unsigned int bm_lds[2];

    const int b  = blockIdx.x;
    const int hn = b >> 6;                       // h*BATCH + n
    const int s0 = (b & 63) * RPB;
    const int n  = hn & 3;
    const int h  = hn >> 2;
    const int base_hn = hn * SEQ * CDIM;

    const int r_loc = threadIdx.x >> 3;          // 0..31 (query row in block)
    const int sub   = threadIdx.x & 7;
    const int c0    = sub * 4;
    const int s     = s0 + r_loc;
    const int row   = hn * SEQ + s;

    // ---- prefetch Q and G early (overlaps with staging latency) ----
    float4 q = *(const float4*)&Q[row * CDIM + c0];
    const float4 g = *(const float4*)&G[row * CDIM + c0];

    // ---- band invalid mask: one ballot by wave 0 ----
    if (threadIdx.x < 64) {
        const int i  = threadIdx.x;
        const int t  = s0 - WINDOW + i;
        const int tc = min(max(t, 0), SEQ - 1);
        const bool invalid =
            (i < BAND) && ((t < 0) || (t >= SEQ) || (seqMask[n * SEQ + tc] != 0));
        const unsigned long long bmw = __ballot(invalid);
        if (threadIdx.x == 0) {
            bm_lds[0] = (unsigned int)bmw;
            bm_lds[1] = (unsigned int)(bmw >> 32);
        }
    }

    // ---- stage K band only (416 float4 tasks over 256 threads) ----
#pragma unroll
    for (int it = 0; it < 2; ++it) {
        const int task = threadIdx.x + it * 256;
        if (task < BAND * 8) {
            const int i  = task >> 3;
            const int ch = (task & 7) * 4;
            const int t  = s0 - WINDOW + i;
            const int tc = min(max(t, 0), SEQ - 1);
            *(float4*)&k_lds[i][ch] = *(const float4*)&K[base_hn + tc * CDIM + ch];
        }
    }
    __syncthreads();

    // log2-domain softmax: fold 1/sqrt(32) * log2(e) into the Q scale,
    // then exp() becomes a single v_exp_f32 (2^x) per score.
    const float scale = 0.17677669529663687f * 1.4426950408889634f;
    q.x *= scale; q.y *= scale; q.z *= scale; q.w *= scale;

    const unsigned long long bm =
        ((unsigned long long)bm_lds[1] << 32) | (unsigned long long)bm_lds[0];
    const unsigned int mybm = (unsigned int)(bm >> r_loc);

    // ---- QK^T from LDS ----
    float sc[WSZ];
#pragma unroll
    for (int j = 0; j < WSZ; ++j) {
        const float4 k = *(const float4*)&k_lds[r_loc + j][c0];
        float part = fmaf(q.x, k.x, fmaf(q.y, k.y, fmaf(q.z, k.z, q.w * k.w)));
        part = DPP_ADD(part, 0xB1);
        part = DPP_ADD(part, 0x4E);
        part = DPP_ADD(part, 0x141);
        sc[j] = ((mybm >> j) & 1u) ? -1e30f : part;
    }

    // ---- softmax over 21 log2-domain scores ----
    float m = -1e30f;
#pragma unroll
    for (int j = 0; j < WSZ; ++j) m = fmaxf(m, sc[j]);
    float sum = 0.f;
#pragma unroll
    for (int j = 0; j < WSZ; ++j) {
        const float e = __builtin_amdgcn_exp2f(sc[j] - m);
        sc[j] = e;
        sum += e;
    }
    const float inv = 1.0f / sum;

    // ---- PV from GLOBAL (L1-resident band) + gate ----
    const float* __restrict__ vbase = V + base_hn + c0;
    float4 acc = make_float4(0.f, 0.f, 0.f, 0.f);
#pragma unroll
    for (int j = 0; j < WSZ; ++j) {
        const int t  = s - WINDOW + j;
        const int tc = min(max(t, 0), SEQ - 1);
        const float4 v = *(const float4*)&vbase[tc * CDIM];
        acc.x = fmaf(sc[j], v.x, acc.x);
        acc.y = fmaf(sc[j], v.y, acc.y);
        acc.z = fmaf(sc[j], v.z, acc.z);
        acc.w = fmaf(sc[j], v.w, acc.w);
    }

    float4 o;
    o.x = acc.x * inv * g.x;
    o.y = acc.y * inv * g.y;
    o.z = acc.z * inv * g.z;
    o.w = acc.w * inv * g.w;

    // out[n, s, h, i]
    *(float4*)&out[((n * SEQ + s) * HEADS + h) * CDIM + c0] = o;
}

extern "C" void kernel_launch(void* const* d_in, const int* in_sizes, int n_in,
                              void* d_out, int out_size, void* d_ws, size_t ws_size,
                              hipStream_t stream) {
    const float* Q = (const float*)d_in[0];
    const float* K = (const float*)d_in[1];
    const float* V = (const float*)d_in[2];
    const float* G = (const float*)d_in[3];
    const unsigned char* seqMask = (const unsigned char*)d_in[4];
    float* out = (float*)d_out;

    const int blocks = HEADS * BATCH * (SEQ / RPB);   // 2048
    lwin_attn_kernel<<<blocks, 256, 0, stream>>>(Q, K, V, G, seqMask, out);
}

// Round 6
// 14.269 us; speedup vs baseline: 1.2738x; 1.2738x over previous
//
#include <hip/hip_runtime.h>
#include <math.h>

#define HEADS 8
#define BATCH 4
#define SEQ 2048
#define CDIM 32
#define WINDOW 10
#define WSZ 21                       // keys per query row
#define RPB 32                       // query rows per block
#define BAND (RPB + 2 * WINDOW)      // 52 band rows staged in LDS
#define KV_TASKS (2 * BAND * 8)      // 832 float4 staging tasks (K then V)

// DPP cross-lane add (pure VALU). xor1 = quad_perm 0xB1, xor2 = quad_perm
// 0x4E, cross-quad within 8-lane group = row_half_mirror 0x141.
#define DPP_ADD(x, ctrl) \
    ((x) + __int_as_float(__builtin_amdgcn_mov_dpp(__float_as_int(x), (ctrl), 0xF, 0xF, true)))

__global__ __launch_bounds__(256) void lwin_attn_kernel(
    const float* __restrict__ Q, const float* __restrict__ K,
    const float* __restrict__ V, const float* __restrict__ G,
    const unsigned char* __restrict__ seqMask, float* __restrict__ out)
{
    __shared__ float kv[2 * BAND * CDIM];   // K band then V band, contiguous (13312 B)
    __shared__ unsigned int bm_lds[2];

    // XCD-aware swizzle: dispatch index d -> original block b so XCD (d%8)
    // owns a contiguous 256-block chunk (4 full (h,n) panels ~= 4 MB = L2).
    // Adjacent bands overlap 20/32 rows -> L2 hits instead of L3 round-trips.
    const int d = blockIdx.x;
    const int b = (d & 7) * 256 + (d >> 3);

    const int hn = b >> 6;                       // h*BATCH + n
    const int s0 = (b & 63) * RPB;
    const int n  = hn & 3;
    const int h  = hn >> 2;
    const int base_hn = hn * SEQ * CDIM;

    const int r_loc = threadIdx.x >> 3;          // 0..31 (query row in block)
    const int sub   = threadIdx.x & 7;
    const int c0    = sub * 4;
    const int s     = s0 + r_loc;
    const int row   = hn * SEQ + s;

    // ---- prefetch Q and G early (overlap with staging latency) ----
    float4 q = *(const float4*)&Q[row * CDIM + c0];
    const float4 g = *(const float4*)&G[row * CDIM + c0];

    // ---- band invalid mask: one ballot by wave 0 ----
    if (threadIdx.x < 64) {
        const int i  = threadIdx.x;
        const int t  = s0 - WINDOW + i;
        const int tc = min(max(t, 0), SEQ - 1);
        const bool invalid =
            (i < BAND) && ((t < 0) || (t >= SEQ) || (seqMask[n * SEQ + tc] != 0));
        const unsigned long long bmw = __ballot(invalid);
        if (threadIdx.x == 0) {
            bm_lds[0] = (unsigned int)bmw;
            bm_lds[1] = (unsigned int)(bmw >> 32);
        }
    }

    // ---- stage K+V band via async global->LDS (13 full waves of tasks) ----
    const int wv   = threadIdx.x >> 6;
    const int lane = threadIdx.x & 63;
#if defined(__has_builtin) && __has_builtin(__builtin_amdgcn_global_load_lds)
    for (int t = wv; t < KV_TASKS / 64; t += 4) {   // t = 0..12
        const int task = t * 64 + lane;
        const bool isK = task < BAND * 8;
        const int  tt  = isK ? task : task - BAND * 8;
        const int  i   = tt >> 3;
        const int  ch  = (tt & 7) * 4;
        const int  tr  = s0 - WINDOW + i;
        const int  tc  = min(max(tr, 0), SEQ - 1);
        const float* src = (isK ? K : V) + base_hn + tc * CDIM + ch;
        // LDS dest: wave-uniform base + lane*16 (task-linear layout, K|V
        // boundary at task 416 falls exactly at the V region start).
        __builtin_amdgcn_global_load_lds(
            (const __attribute__((address_space(1))) void*)src,
            (__attribute__((address_space(3))) void*)(kv + t * 256),
            16, 0, 0);
    }
#else
    for (int it = 0; it < 4; ++it) {
        const int task = threadIdx.x + it * 256;
        if (task < KV_TASKS) {
            const bool isK = task < BAND * 8;
            const int  tt  = isK ? task : task - BAND * 8;
            const int  i   = tt >> 3;
            const int  ch  = (tt & 7) * 4;
            const int  tr  = s0 - WINDOW + i;
            const int  tc  = min(max(tr, 0), SEQ - 1);
            const float* src = (isK ? K : V) + base_hn + tc * CDIM + ch;
            *(float4*)&kv[task * 4] = *(const float4*)src;
        }
    }
#endif
    __syncthreads();

    // log2-domain softmax: fold 1/sqrt(32)*log2(e) into the Q scale.
    const float scale = 0.17677669529663687f * 1.4426950408889634f;
    q.x *= scale; q.y *= scale; q.z *= scale; q.w *= scale;

    const unsigned long long bm =
        ((unsigned long long)bm_lds[1] << 32) | (unsigned long long)bm_lds[0];
    const unsigned int mybm = (unsigned int)(bm >> r_loc);

    const float* __restrict__ k_l = kv;
    const float* __restrict__ v_l = kv + BAND * CDIM;

    // ---- QK^T from LDS ----
    float sc[WSZ];
#pragma unroll
    for (int j = 0; j < WSZ; ++j) {
        const float4 k = *(const float4*)&k_l[(r_loc + j) * CDIM + c0];
        float part = fmaf(q.x, k.x, fmaf(q.y, k.y, fmaf(q.z, k.z, q.w * k.w)));
        part = DPP_ADD(part, 0xB1);
        part = DPP_ADD(part, 0x4E);
        part = DPP_ADD(part, 0x141);
        sc[j] = ((mybm >> j) & 1u) ? -1e30f : part;
    }

    // ---- softmax over 21 log2-domain scores ----
    float m = -1e30f;
#pragma unroll
    for (int j = 0; j < WSZ; ++j) m = fmaxf(m, sc[j]);
    float sum = 0.f;
#pragma unroll
    for (int j = 0; j < WSZ; ++j) {
        const float e = __builtin_amdgcn_exp2f(sc[j] - m);
        sc[j] = e;
        sum += e;
    }
    const float inv = 1.0f / sum;

    // ---- PV from LDS + gate ----
    float4 acc = make_float4(0.f, 0.f, 0.f, 0.f);
#pragma unroll
    for (int j = 0; j < WSZ; ++j) {
        const float4 v = *(const float4*)&v_l[(r_loc + j) * CDIM + c0];
        acc.x = fmaf(sc[j], v.x, acc.x);
        acc.y = fmaf(sc[j], v.y, acc.y);
        acc.z = fmaf(sc[j], v.z, acc.z);
        acc.w = fmaf(sc[j], v.w, acc.w);
    }

    float4 o;
    o.x = acc.x * inv * g.x;
    o.y = acc.y * inv * g.y;
    o.z = acc.z * inv * g.z;
    o.w = acc.w * inv * g.w;

    // out[n, s, h, i]
    *(float4*)&out[((n * SEQ + s) * HEADS + h) * CDIM + c0] = o;
}

extern "C" void kernel_launch(void* const* d_in, const int* in_sizes, int n_in,
                              void* d_out, int out_size, void* d_ws, size_t ws_size,
                              hipStream_t stream) {
    const float* Q = (const float*)d_in[0];
    const float* K = (const float*)d_in[1];
    const float* V = (const float*)d_in[2];
    const float* G = (const float*)d_in[3];
    const unsigned char* seqMask = (const unsigned char*)d_in[4];
    float* out = (float*)d_out;

    const int blocks = HEADS * BATCH * (SEQ / RPB);   // 2048
    lwin_attn_kernel<<<blocks, 256, 0, stream>>>(Q, K, V, G, seqMask, out);
}